// Round 4
// baseline (11087.450 us; speedup 1.0000x reference)
//
#include <hip/hip_runtime.h>

typedef unsigned short ushortT;
typedef float floatx4 __attribute__((ext_vector_type(4)));
typedef unsigned int uintx4 __attribute__((ext_vector_type(4)));

#define D_MODEL 2048
#define HEAD_DIM 128
#define NUM_HEADS 16
#define SEQ 2048
#define BATCH 2
#define M_TOK (BATCH * SEQ)                      // 4096 token rows
#define QKV_ELEMS ((size_t)M_TOK * D_MODEL)      // 8388608 elems per buffer

__device__ __forceinline__ float bf2f(ushortT h) {
    return __uint_as_float(((unsigned int)h) << 16);
}
__device__ __forceinline__ ushortT f2bf(float f) {
    unsigned int u = __float_as_uint(f);
    u = u + 0x7fffu + ((u >> 16) & 1u);   // round-to-nearest-even
    return (ushortT)(u >> 16);
}

// ---------------------------------------------------------------------------
// Runtime dtype detection (unchanged — it demonstrably routed correctly).
// flags[i]=1 means bf16; flags[7]=1 constant for our own bf16 intermediates.
// ---------------------------------------------------------------------------
__global__ __launch_bounds__(256) void detect_kernel(
    const void* x, const void* wq, const void* wk, const void* wv,
    const void* wo, const void* bo, const void* th, int* flags)
{
    __shared__ int cnt[256];
    const int tid = threadIdx.x;
    const int t = tid >> 5;
    const int l = tid & 31;
    const void* ptrs[8] = {x, wq, wk, wv, wo, bo, th, x};
    int sane = 0;
    if (t < 7) {
        ushortT u = ((const ushortT*)ptrs[t])[2 * l];
        int e = (u >> 7) & 0xff;
        sane = (e >= 0x68 && e <= 0x88) ? 1 : 0;
    }
    cnt[tid] = sane;
    __syncthreads();
    if (tid < 8) {
        int s = 0;
        #pragma unroll
        for (int i = 0; i < 32; i++) s += cnt[tid * 32 + i];
        flags[tid] = (tid == 7) ? 1 : (s > 16 ? 1 : 0);
    }
}

__device__ __forceinline__ float gload(const void* p, size_t i, bool isbf) {
    return isbf ? bf2f(((const ushortT*)p)[i]) : ((const float*)p)[i];
}

// ---------------------------------------------------------------------------
// Naive fp32 GEMM: C[M x 2048] = A[M x 2048] @ W[2048 x 2048]^T (+ bias).
// Tile 64x64x16, 256 threads, 4x4 micro-tile. outF32 selects output dtype:
// fp32 (final projection -> d_out) or bf16 (intermediates).
// ---------------------------------------------------------------------------
__global__ __launch_bounds__(256) void gemm_f32(
    const void* __restrict__ A,
    const void* __restrict__ W0, const void* __restrict__ W1, const void* __restrict__ W2,
    void* C0, void* C1, void* C2,
    const void* __restrict__ bias,
    const int* __restrict__ flags, int aFlag, int wFlagBase, int biasFlag,
    int outF32)
{
    __shared__ float As[16][68];   // [k][m]
    __shared__ float Ws[16][68];   // [k][n]

    const int z = blockIdx.z;
    const void* W = (z == 0) ? W0 : (z == 1 ? W1 : W2);
    void* C = (z == 0) ? C0 : (z == 1 ? C1 : C2);

    const bool abf = flags[aFlag] != 0;
    const bool wbf = flags[wFlagBase + z] != 0;
    const bool bbf = flags[biasFlag] != 0;

    const int tid = threadIdx.x;
    const int tx = tid & 15;           // n-dir thread 0..15
    const int ty = tid >> 4;           // m-dir thread 0..15
    const int lm = tid >> 2;           // staging row 0..63
    const int lk = (tid & 3) * 4;      // staging k offset {0,4,8,12}

    const int blockM = blockIdx.y * 64;
    const int blockN = blockIdx.x * 64;

    float acc[4][4] = {};

    for (int k0 = 0; k0 < D_MODEL; k0 += 16) {
        __syncthreads();
        #pragma unroll
        for (int j = 0; j < 4; j++) {
            As[lk + j][lm] = gload(A, (size_t)(blockM + lm) * D_MODEL + k0 + lk + j, abf);
            Ws[lk + j][lm] = gload(W, (size_t)(blockN + lm) * D_MODEL + k0 + lk + j, wbf);
        }
        __syncthreads();

        #pragma unroll
        for (int k = 0; k < 16; k++) {
            floatx4 a = *(const floatx4*)&As[k][ty * 4];
            floatx4 b = *(const floatx4*)&Ws[k][tx * 4];
            #pragma unroll
            for (int i = 0; i < 4; i++)
                #pragma unroll
                for (int j = 0; j < 4; j++)
                    acc[i][j] += a[i] * b[j];
        }
    }

    #pragma unroll
    for (int j = 0; j < 4; j++) {
        const int n = blockN + tx * 4 + j;
        float bval = 0.f;
        if (bias) bval = bbf ? bf2f(((const ushortT*)bias)[n])
                             : ((const float*)bias)[n];
        #pragma unroll
        for (int i = 0; i < 4; i++) {
            const int m = blockM + ty * 4 + i;
            const float val = acc[i][j] + bval;
            if (outF32) ((float*)C)[(size_t)m * D_MODEL + n] = val;
            else        ((ushortT*)C)[(size_t)m * D_MODEL + n] = f2bf(val);
        }
    }
}

// ---------------------------------------------------------------------------
// RoPE in-place on bf16 q and k (unchanged).
// ---------------------------------------------------------------------------
__global__ __launch_bounds__(64) void rope_kernel(
    ushortT* __restrict__ qb, ushortT* __restrict__ kb,
    const void* __restrict__ theta, const int* __restrict__ flags)
{
    const int tok = blockIdx.x;          // 0..4095
    const int h   = blockIdx.y;          // 0..15
    ushortT* p = (blockIdx.z ? kb : qb) + (size_t)tok * D_MODEL + h * HEAD_DIM;
    const int d = threadIdx.x;           // 0..63
    const int t = tok & (SEQ - 1);

    const float th = (flags[6] != 0) ? bf2f(((const ushortT*)theta)[d])
                                     : ((const float*)theta)[d];
    const float fr = (float)t * th;
    const float s = sinf(fr);
    const float c = cosf(fr);

    const float ve = bf2f(p[2 * d]);
    const float vo = bf2f(p[2 * d + 1]);
    __syncthreads();                     // all reads before any in-place writes
    p[d]      = f2bf(ve * c - vo * s);
    p[d + 64] = f2bf(ve * s + vo * c);
}

// ---------------------------------------------------------------------------
// Causal attention (unchanged).
// ---------------------------------------------------------------------------
__global__ __launch_bounds__(256) void attn_kernel(
    const ushortT* __restrict__ q, const ushortT* __restrict__ k,
    const ushortT* __restrict__ v, ushortT* __restrict__ ctx)
{
    __shared__ float qv[HEAD_DIM];
    __shared__ float sc[SEQ];
    __shared__ float red[256];

    const int tpos = blockIdx.x;
    const int bh   = blockIdx.y;
    const int b    = bh >> 4;
    const int h    = bh & 15;
    const size_t base = (size_t)b * SEQ * D_MODEL + h * HEAD_DIM;
    const size_t qoff = base + (size_t)tpos * D_MODEL;
    const int tid  = threadIdx.x;
    const int nk   = tpos + 1;

    if (tid < HEAD_DIM) qv[tid] = bf2f(q[qoff + tid]);
    __syncthreads();

    // Pass 1: scores
    float lmax = -INFINITY;
    for (int kk = tid; kk < nk; kk += 256) {
        const ushortT* kr = k + base + (size_t)kk * D_MODEL;
        float acc = 0.f;
        #pragma unroll
        for (int i = 0; i < 16; i++) {
            uintx4 u = *(const uintx4*)(kr + i * 8);
            const float* qp = &qv[i * 8];
            acc += __uint_as_float(u.x << 16)          * qp[0];
            acc += __uint_as_float(u.x & 0xffff0000u)  * qp[1];
            acc += __uint_as_float(u.y << 16)          * qp[2];
            acc += __uint_as_float(u.y & 0xffff0000u)  * qp[3];
            acc += __uint_as_float(u.z << 16)          * qp[4];
            acc += __uint_as_float(u.z & 0xffff0000u)  * qp[5];
            acc += __uint_as_float(u.w << 16)          * qp[6];
            acc += __uint_as_float(u.w & 0xffff0000u)  * qp[7];
        }
        acc *= 0.08838834764831845f;     // 1/sqrt(128)
        sc[kk] = acc;
        lmax = fmaxf(lmax, acc);
    }

    red[tid] = lmax; __syncthreads();
    #pragma unroll
    for (int s = 128; s > 0; s >>= 1) {
        if (tid < s) red[tid] = fmaxf(red[tid], red[tid + s]);
        __syncthreads();
    }
    const float gmax = red[0];
    __syncthreads();

    // Pass 2: exp + sum
    float lsum = 0.f;
    for (int kk = tid; kk < nk; kk += 256) {
        float p = __expf(sc[kk] - gmax);
        sc[kk] = p;
        lsum += p;
    }
    red[tid] = lsum; __syncthreads();
    #pragma unroll
    for (int s = 128; s > 0; s >>= 1) {
        if (tid < s) red[tid] += red[tid + s];
        __syncthreads();
    }
    const float inv = 1.f / red[0];
    __syncthreads();

    // Pass 3: ctx[d] = sum_k p[k] * V[k][d]
    const int d = tid & 127;
    const int half = tid >> 7;
    const ushortT* vp = v + base + d;
    float acc = 0.f;
    for (int kk = half; kk < nk; kk += 2)
        acc += sc[kk] * bf2f(vp[(size_t)kk * D_MODEL]);

    red[tid] = acc; __syncthreads();
    if (tid < HEAD_DIM)
        ctx[qoff + tid] = f2bf((red[tid] + red[tid + 128]) * inv);
}

// ---------------------------------------------------------------------------
extern "C" void kernel_launch(void* const* d_in, const int* in_sizes, int n_in,
                              void* d_out, int out_size, void* d_ws, size_t ws_size,
                              hipStream_t stream) {
    const void* x     = d_in[0];
    const void* Wq    = d_in[1];
    const void* Wk    = d_in[2];
    const void* Wv    = d_in[3];
    const void* Wo    = d_in[4];
    const void* bo    = d_in[5];
    const void* theta = d_in[6];

    ushortT* ws  = (ushortT*)d_ws;
    ushortT* qb  = ws;
    ushortT* kb  = ws + QKV_ELEMS;
    ushortT* vb  = ws + 2 * QKV_ELEMS;
    ushortT* cxb = ws + 3 * QKV_ELEMS;
    int* flags   = (int*)(ws + 4 * QKV_ELEMS);

    // 0. dtype flags (1 = bf16, 0 = fp32); flags[7] = 1 for our intermediates
    detect_kernel<<<1, 256, 0, stream>>>(x, Wq, Wk, Wv, Wo, bo, theta, flags);

    // 1. QKV projections -> bf16 intermediates
    gemm_f32<<<dim3(D_MODEL / 64, M_TOK / 64, 3), 256, 0, stream>>>(
        x, Wq, Wk, Wv, qb, kb, vb, nullptr, flags, 0, 1, 5, /*outF32=*/0);

    // 2. RoPE on q and k
    rope_kernel<<<dim3(M_TOK, NUM_HEADS, 2), 64, 0, stream>>>(qb, kb, theta, flags);

    // 3. Causal attention -> bf16 ctx
    attn_kernel<<<dim3(SEQ, BATCH * NUM_HEADS), 256, 0, stream>>>(qb, kb, vb, cxb);

    // 4. Output projection + bias -> FP32 d_out (the reference's output dtype)
    gemm_f32<<<dim3(D_MODEL / 64, M_TOK / 64, 1), 256, 0, stream>>>(
        cxb, Wo, Wo, Wo, d_out, d_out, d_out, bo, flags, 7, 4, 5, /*outF32=*/1);
}

// Round 5
// 958.960 us; speedup vs baseline: 11.5620x; 11.5620x over previous
//
#include <hip/hip_runtime.h>

typedef unsigned short ushortT;
typedef short short8 __attribute__((ext_vector_type(8)));
typedef float floatx4 __attribute__((ext_vector_type(4)));

#define D_MODEL 2048
#define HEAD_DIM 128
#define NUM_HEADS 16
#define SEQ 2048
#define BATCH 2
#define M_TOK (BATCH * SEQ)                      // 4096 token rows
#define QKV_ELEMS ((size_t)M_TOK * D_MODEL)      // 8388608 elems per buffer

__device__ __forceinline__ float bf2f(ushortT h) {
    return __uint_as_float(((unsigned int)h) << 16);
}
__device__ __forceinline__ ushortT f2bf(float f) {
    unsigned int u = __float_as_uint(f);
    u = u + 0x7fffu + ((u >> 16) & 1u);   // round-to-nearest-even
    return (ushortT)(u >> 16);
}

// Load 8 consecutive elements as bf16 frag, converting from fp32 if needed.
template<bool BF>
__device__ __forceinline__ short8 g_load8(const void* p, size_t idx) {
    if constexpr (BF) {
        return *(const short8*)((const ushortT*)p + idx);
    } else {
        const float* f = (const float*)p + idx;
        floatx4 a = *(const floatx4*)f;
        floatx4 b = *(const floatx4*)(f + 4);
        short8 r;
        r[0] = (short)f2bf(a.x); r[1] = (short)f2bf(a.y);
        r[2] = (short)f2bf(a.z); r[3] = (short)f2bf(a.w);
        r[4] = (short)f2bf(b.x); r[5] = (short)f2bf(b.y);
        r[6] = (short)f2bf(b.z); r[7] = (short)f2bf(b.w);
        return r;
    }
}

// ---------------------------------------------------------------------------
// MFMA GEMM (bisect-validated core): C[M x 2048] = A @ W^T (+bias).
// 64x64 block tile, 4 waves, mfma_f32_16x16x32_bf16, fp32 accumulate.
// ABF/WBF: input dtypes. OUTF32: fp32 output (final proj) vs bf16.
// ---------------------------------------------------------------------------
template<bool ABF, bool WBF, bool OUTF32>
__global__ __launch_bounds__(256) void gemm_bt(
    const void* __restrict__ A,
    const void* __restrict__ W0, const void* __restrict__ W1, const void* __restrict__ W2,
    void* C0, void* C1, void* C2,
    const float* __restrict__ bias)
{
    __shared__ short As[64 * 40];   // stride 40 shorts: conflict-free frag reads
    __shared__ short Bs[64 * 40];

    const int z = blockIdx.z;
    const void* W = (z == 0) ? W0 : (z == 1 ? W1 : W2);
    void* C = (z == 0) ? C0 : (z == 1 ? C1 : C2);

    const int tid  = threadIdx.x;
    const int wave = tid >> 6;
    const int lane = tid & 63;
    const int lr   = lane & 15;
    const int q4   = lane >> 4;
    const int kA   = q4 * 8;

    const int r  = tid >> 2;             // staging row 0..63
    const int c8 = (tid & 3) * 8;        // staging k offset {0,8,16,24}

    const int blockM = blockIdx.y * 64;
    const int blockN = blockIdx.x * 64;

    const size_t aBase = (size_t)(blockM + r) * D_MODEL + c8;
    const size_t bBase = (size_t)(blockN + r) * D_MODEL + c8;

    floatx4 acc0 = {0.f, 0.f, 0.f, 0.f};
    floatx4 acc1 = {0.f, 0.f, 0.f, 0.f};
    floatx4 acc2 = {0.f, 0.f, 0.f, 0.f};
    floatx4 acc3 = {0.f, 0.f, 0.f, 0.f};

    for (int kk = 0; kk < D_MODEL; kk += 32) {
        short8 av = g_load8<ABF>(A, aBase + kk);
        short8 bv = g_load8<WBF>(W, bBase + kk);
        __syncthreads();   // previous iter's frag reads complete
        *(short8*)(&As[r * 40 + c8]) = av;
        *(short8*)(&Bs[r * 40 + c8]) = bv;
        __syncthreads();

        short8 af  = *(const short8*)(&As[(wave * 16 + lr) * 40 + kA]);
        short8 bf0 = *(const short8*)(&Bs[( 0 + lr) * 40 + kA]);
        short8 bf1 = *(const short8*)(&Bs[(16 + lr) * 40 + kA]);
        short8 bf2 = *(const short8*)(&Bs[(32 + lr) * 40 + kA]);
        short8 bf3 = *(const short8*)(&Bs[(48 + lr) * 40 + kA]);

        acc0 = __builtin_amdgcn_mfma_f32_16x16x32_bf16(af, bf0, acc0, 0, 0, 0);
        acc1 = __builtin_amdgcn_mfma_f32_16x16x32_bf16(af, bf1, acc1, 0, 0, 0);
        acc2 = __builtin_amdgcn_mfma_f32_16x16x32_bf16(af, bf2, acc2, 0, 0, 0);
        acc3 = __builtin_amdgcn_mfma_f32_16x16x32_bf16(af, bf3, acc3, 0, 0, 0);
    }

    const int rowBase = blockM + wave * 16 + q4 * 4;
    const int colBase = blockN + lr;
    #pragma unroll
    for (int tn = 0; tn < 4; tn++) {
        floatx4 acc = (tn == 0) ? acc0 : (tn == 1) ? acc1 : (tn == 2) ? acc2 : acc3;
        const int col = colBase + tn * 16;
        const float bval = bias ? bias[col] : 0.f;
        #pragma unroll
        for (int rr = 0; rr < 4; rr++) {
            const float val = acc[rr] + bval;
            if constexpr (OUTF32)
                ((float*)C)[(size_t)(rowBase + rr) * D_MODEL + col] = val;
            else
                ((ushortT*)C)[(size_t)(rowBase + rr) * D_MODEL + col] = f2bf(val);
        }
    }
}

// ---------------------------------------------------------------------------
// RoPE in-place on bf16 q and k. One block per (token, tensor); 256 threads
// cover 16 heads x 64 rotation pairs in 4 iterations.
// ---------------------------------------------------------------------------
__global__ __launch_bounds__(256) void rope_kernel(
    ushortT* __restrict__ qb, ushortT* __restrict__ kb,
    const float* __restrict__ theta)
{
    const int tok = blockIdx.x;
    ushortT* p = (blockIdx.y ? kb : qb) + (size_t)tok * D_MODEL;
    const int t = tok & (SEQ - 1);
    const int tid = threadIdx.x;
    const int d = tid & 63;
    const int hb = tid >> 6;             // 0..3

    const float fr = (float)t * theta[d];
    const float s = sinf(fr);
    const float c = cosf(fr);

    float ve[4], vo[4];
    #pragma unroll
    for (int i = 0; i < 4; i++) {
        ushortT* ph = p + (i * 4 + hb) * HEAD_DIM;
        ve[i] = bf2f(ph[2 * d]);
        vo[i] = bf2f(ph[2 * d + 1]);
    }
    __syncthreads();                     // all reads before any in-place writes
    #pragma unroll
    for (int i = 0; i < 4; i++) {
        ushortT* ph = p + (i * 4 + hb) * HEAD_DIM;
        ph[d]      = f2bf(ve[i] * c - vo[i] * s);
        ph[d + 64] = f2bf(ve[i] * s + vo[i] * c);
    }
}

// ---------------------------------------------------------------------------
// V transpose: vb[(b*SEQ+t)*D_MODEL + h*128 + d] -> vt[(bh*128+d)*SEQ + t]
// 32x32 LDS tiles, coalesced both sides.
// ---------------------------------------------------------------------------
__global__ __launch_bounds__(256) void vtrans_kernel(
    const ushortT* __restrict__ v, ushortT* __restrict__ vt)
{
    __shared__ ushortT tile[32][33];
    const int t0 = blockIdx.x * 32;
    const int d0 = blockIdx.y * 32;
    const int bh = blockIdx.z;
    const int b = bh >> 4, h = bh & 15;
    const int tx = threadIdx.x & 31;
    const int ty = threadIdx.x >> 5;     // 0..7

    #pragma unroll
    for (int i = 0; i < 4; i++) {
        const int t = t0 + ty + i * 8;
        tile[tx][ty + i * 8] =
            v[(size_t)(b * SEQ + t) * D_MODEL + h * HEAD_DIM + d0 + tx];
    }
    __syncthreads();
    #pragma unroll
    for (int i = 0; i < 4; i++) {
        const int d = d0 + ty + i * 8;
        vt[(size_t)(bh * HEAD_DIM + d) * SEQ + t0 + tx] = tile[ty + i * 8][tx];
    }
}

// ---------------------------------------------------------------------------
// Barrier-free MFMA flash attention.
// Block = (64-row Q-tile, bh); wave w owns q-rows [qt*64+w*16, +16).
// K/V frags direct from global (V pre-transposed); P via wave-private LDS.
// ---------------------------------------------------------------------------
__global__ __launch_bounds__(256) void flash_attn(
    const ushortT* __restrict__ q, const ushortT* __restrict__ k,
    const ushortT* __restrict__ vt, ushortT* __restrict__ ctx)
{
    __shared__ short Pl[4][16][72];      // per-wave P [q][kt], stride 72 (16B-aligned)

    const int qt = blockIdx.x;
    const int bh = blockIdx.y;
    const int b = bh >> 4, h = bh & 15;
    const size_t base  = (size_t)b * SEQ * D_MODEL + h * HEAD_DIM;  // q,k,ctx
    const size_t vbase = (size_t)bh * HEAD_DIM * SEQ;               // vt [d][t]
    const int tid = threadIdx.x;
    const int w = tid >> 6, lane = tid & 63;
    const int lr = lane & 15, quad = lane >> 4;
    const int q0 = qt * 64 + w * 16;
    short* myP = &Pl[w][0][0];

    // Q A-frags in registers, 1/sqrt(HD) folded in.
    short8 Qf[4];
    {
        const ushortT* qrow = q + base + (size_t)(q0 + lr) * D_MODEL + quad * 8;
        #pragma unroll
        for (int ks = 0; ks < 4; ks++) {
            short8 raw = *(const short8*)(qrow + ks * 32);
            #pragma unroll
            for (int j = 0; j < 8; j++)
                Qf[ks][j] = (short)f2bf(bf2f((ushortT)raw[j]) * 0.08838834764831845f);
        }
    }

    floatx4 Of[8];
    #pragma unroll
    for (int i = 0; i < 8; i++) Of[i] = (floatx4){0.f, 0.f, 0.f, 0.f};
    float m_i[4] = {-INFINITY, -INFINITY, -INFINITY, -INFINITY};
    float l_i[4] = {0.f, 0.f, 0.f, 0.f};

    for (int kt0 = 0; kt0 <= qt * 64; kt0 += 64) {
        // --- S = Q K^T (scaled), C-layout: S[q=quad*4+i][kt=16*sub+lr] ---
        floatx4 Sf[4];
        #pragma unroll
        for (int sub = 0; sub < 4; sub++) {
            floatx4 acc = {0.f, 0.f, 0.f, 0.f};
            const ushortT* krow =
                k + base + (size_t)(kt0 + sub * 16 + lr) * D_MODEL + quad * 8;
            #pragma unroll
            for (int ks = 0; ks < 4; ks++) {
                short8 Kf = *(const short8*)(krow + ks * 32);
                acc = __builtin_amdgcn_mfma_f32_16x16x32_bf16(Qf[ks], Kf, acc, 0, 0, 0);
            }
            Sf[sub] = acc;
        }

        // --- causal mask (diagonal tile only) ---
        if (kt0 == qt * 64) {
            #pragma unroll
            for (int sub = 0; sub < 4; sub++) {
                const int ktg = kt0 + sub * 16 + lr;
                #pragma unroll
                for (int i = 0; i < 4; i++)
                    if (ktg > q0 + quad * 4 + i) Sf[sub][i] = -1e30f;
            }
        }

        // --- online softmax: row stats live in one quad ---
        float mn[4], alpha[4], rs[4];
        #pragma unroll
        for (int i = 0; i < 4; i++) {
            float t = fmaxf(fmaxf(Sf[0][i], Sf[1][i]), fmaxf(Sf[2][i], Sf[3][i]));
            t = fmaxf(t, __shfl_xor(t, 1));
            t = fmaxf(t, __shfl_xor(t, 2));
            t = fmaxf(t, __shfl_xor(t, 4));
            t = fmaxf(t, __shfl_xor(t, 8));
            mn[i] = fmaxf(m_i[i], t);
            alpha[i] = __expf(m_i[i] - mn[i]);   // exp(-inf)=0 first iter
            m_i[i] = mn[i];
            rs[i] = 0.f;
        }
        #pragma unroll
        for (int sub = 0; sub < 4; sub++) {
            #pragma unroll
            for (int i = 0; i < 4; i++) {
                const float p = __expf(Sf[sub][i] - mn[i]);
                rs[i] += p;
                myP[(quad * 4 + i) * 72 + sub * 16 + lr] = (short)f2bf(p);
            }
        }
        #pragma unroll
        for (int i = 0; i < 4; i++) {
            float t = rs[i];
            t += __shfl_xor(t, 1);
            t += __shfl_xor(t, 2);
            t += __shfl_xor(t, 4);
            t += __shfl_xor(t, 8);
            l_i[i] = l_i[i] * alpha[i] + t;
        }
        #pragma unroll
        for (int dsub = 0; dsub < 8; dsub++)
            #pragma unroll
            for (int i = 0; i < 4; i++) Of[dsub][i] *= alpha[i];

        // --- P: C-layout -> A-layout via wave-private LDS ---
        asm volatile("s_waitcnt lgkmcnt(0)" ::: "memory");
        short8 Pf0 = *(const short8*)(myP + lr * 72 + quad * 8);
        short8 Pf1 = *(const short8*)(myP + lr * 72 + 32 + quad * 8);

        // --- O += P V  (V^T direct from global) ---
        #pragma unroll
        for (int dsub = 0; dsub < 8; dsub++) {
            const ushortT* vrow =
                vt + vbase + (size_t)(dsub * 16 + lr) * SEQ + kt0 + quad * 8;
            short8 V0 = *(const short8*)(vrow);
            short8 V1 = *(const short8*)(vrow + 32);
            Of[dsub] = __builtin_amdgcn_mfma_f32_16x16x32_bf16(Pf0, V0, Of[dsub], 0, 0, 0);
            Of[dsub] = __builtin_amdgcn_mfma_f32_16x16x32_bf16(Pf1, V1, Of[dsub], 0, 0, 0);
        }
    }

    // --- epilogue: O / l -> ctx ---
    float inv[4];
    #pragma unroll
    for (int i = 0; i < 4; i++) inv[i] = 1.f / l_i[i];
    #pragma unroll
    for (int dsub = 0; dsub < 8; dsub++)
        #pragma unroll
        for (int i = 0; i < 4; i++)
            ctx[base + (size_t)(q0 + quad * 4 + i) * D_MODEL + dsub * 16 + lr] =
                f2bf(Of[dsub][i] * inv[i]);
}

// ---------------------------------------------------------------------------
extern "C" void kernel_launch(void* const* d_in, const int* in_sizes, int n_in,
                              void* d_out, int out_size, void* d_ws, size_t ws_size,
                              hipStream_t stream) {
    const void*  x     = d_in[0];
    const void*  Wq    = d_in[1];
    const void*  Wk    = d_in[2];
    const void*  Wv    = d_in[3];
    const void*  Wo    = d_in[4];
    const float* bo    = (const float*)d_in[5];
    const float* theta = (const float*)d_in[6];

    ushortT* ws  = (ushortT*)d_ws;
    ushortT* qb  = ws;                     // Q (bf16)
    ushortT* kb  = ws + QKV_ELEMS;         // K (bf16)
    ushortT* vb  = ws + 2 * QKV_ELEMS;     // V, then reused as ctx
    ushortT* vtb = ws + 3 * QKV_ELEMS;     // V^T [bh][d][t]

    // 1. QKV projections (fp32 in, bf16 out)
    gemm_bt<false, false, false><<<dim3(D_MODEL / 64, M_TOK / 64, 3), 256, 0, stream>>>(
        x, Wq, Wk, Wv, qb, kb, vb, nullptr);

    // 2. RoPE on q and k
    rope_kernel<<<dim3(M_TOK, 2), 256, 0, stream>>>(qb, kb, theta);

    // 3. V transpose -> vtb
    vtrans_kernel<<<dim3(SEQ / 32, HEAD_DIM / 32, BATCH * NUM_HEADS), 256, 0, stream>>>(
        vb, vtb);

    // 4. Flash attention -> ctx (reuses vb)
    flash_attn<<<dim3(SEQ / 64, BATCH * NUM_HEADS), 256, 0, stream>>>(
        qb, kb, vtb, vb);

    // 5. Output projection + bias (bf16 A, fp32 W, fp32 out)
    gemm_bt<true, false, true><<<dim3(D_MODEL / 64, M_TOK / 64, 1), 256, 0, stream>>>(
        vb, Wo, Wo, Wo, d_out, d_out, d_out, bo);
}

// Round 6
// 713.949 us; speedup vs baseline: 15.5298x; 1.3432x over previous
//
#include <hip/hip_runtime.h>

typedef unsigned short ushortT;
typedef short short8 __attribute__((ext_vector_type(8)));
typedef float floatx4 __attribute__((ext_vector_type(4)));

#define D_MODEL 2048
#define HEAD_DIM 128
#define NUM_HEADS 16
#define SEQ 2048
#define BATCH 2
#define M_TOK (BATCH * SEQ)                      // 4096 token rows
#define QKV_ELEMS ((size_t)M_TOK * D_MODEL)      // 8388608 elems per buffer

__device__ __forceinline__ float bf2f(ushortT h) {
    return __uint_as_float(((unsigned int)h) << 16);
}
__device__ __forceinline__ ushortT f2bf(float f) {
    unsigned int u = __float_as_uint(f);
    u = u + 0x7fffu + ((u >> 16) & 1u);   // round-to-nearest-even
    return (ushortT)(u >> 16);
}

// Load 8 consecutive elements as bf16 frag, converting from fp32 if needed.
template<bool BF>
__device__ __forceinline__ short8 g_load8(const void* p, size_t idx) {
    if constexpr (BF) {
        return *(const short8*)((const ushortT*)p + idx);
    } else {
        const float* f = (const float*)p + idx;
        floatx4 a = *(const floatx4*)f;
        floatx4 b = *(const floatx4*)(f + 4);
        short8 r;
        r[0] = (short)f2bf(a.x); r[1] = (short)f2bf(a.y);
        r[2] = (short)f2bf(a.z); r[3] = (short)f2bf(a.w);
        r[4] = (short)f2bf(b.x); r[5] = (short)f2bf(b.y);
        r[6] = (short)f2bf(b.z); r[7] = (short)f2bf(b.w);
        return r;
    }
}

// ---------------------------------------------------------------------------
// 128x128 MFMA GEMM: C[M x 2048] = A @ W^T (+bias). 4 waves in 2x2 grid,
// each wave 64x64 (4x4 MFMA tiles), BK=32, stride-40 LDS.
// ---------------------------------------------------------------------------
template<bool ABF, bool WBF, bool OUTF32>
__global__ __launch_bounds__(256) void gemm128(
    const void* __restrict__ A,
    const void* __restrict__ W0, const void* __restrict__ W1, const void* __restrict__ W2,
    void* C0, void* C1, void* C2, const float* __restrict__ bias)
{
    __shared__ short As[128 * 40];
    __shared__ short Bs[128 * 40];

    const int z = blockIdx.z;
    const void* W = (z == 0) ? W0 : (z == 1 ? W1 : W2);
    void* C = (z == 0) ? C0 : (z == 1 ? C1 : C2);

    const int tid  = threadIdx.x;
    const int wave = tid >> 6;
    const int lane = tid & 63;
    const int lr   = lane & 15;
    const int quad = lane >> 4;
    const int wm   = (wave & 1) * 64;
    const int wn   = (wave >> 1) * 64;

    const int r   = tid >> 1;          // staging row 0..127
    const int c16 = (tid & 1) * 16;    // staging k offset {0,16}

    const int blockM = blockIdx.y * 128;
    const int blockN = blockIdx.x * 128;

    const size_t aBase = (size_t)(blockM + r) * D_MODEL + c16;
    const size_t bBase = (size_t)(blockN + r) * D_MODEL + c16;

    floatx4 acc[4][4];
    #pragma unroll
    for (int i = 0; i < 4; i++)
        #pragma unroll
        for (int j = 0; j < 4; j++) acc[i][j] = (floatx4){0.f, 0.f, 0.f, 0.f};

    for (int kk = 0; kk < D_MODEL; kk += 32) {
        short8 a0 = g_load8<ABF>(A, aBase + kk);
        short8 a1 = g_load8<ABF>(A, aBase + kk + 8);
        short8 b0 = g_load8<WBF>(W, bBase + kk);
        short8 b1 = g_load8<WBF>(W, bBase + kk + 8);
        __syncthreads();   // previous iter's frag reads complete
        *(short8*)&As[r * 40 + c16]     = a0;
        *(short8*)&As[r * 40 + c16 + 8] = a1;
        *(short8*)&Bs[r * 40 + c16]     = b0;
        *(short8*)&Bs[r * 40 + c16 + 8] = b1;
        __syncthreads();

        short8 af[4], bf[4];
        #pragma unroll
        for (int s = 0; s < 4; s++) {
            af[s] = *(const short8*)&As[(wm + s * 16 + lr) * 40 + quad * 8];
            bf[s] = *(const short8*)&Bs[(wn + s * 16 + lr) * 40 + quad * 8];
        }
        #pragma unroll
        for (int sm = 0; sm < 4; sm++)
            #pragma unroll
            for (int sn = 0; sn < 4; sn++)
                acc[sm][sn] = __builtin_amdgcn_mfma_f32_16x16x32_bf16(
                    af[sm], bf[sn], acc[sm][sn], 0, 0, 0);
    }

    #pragma unroll
    for (int sm = 0; sm < 4; sm++) {
        const int row = blockM + wm + sm * 16 + quad * 4;
        #pragma unroll
        for (int sn = 0; sn < 4; sn++) {
            const int col = blockN + wn + sn * 16 + lr;
            const float bval = bias ? bias[col] : 0.f;
            #pragma unroll
            for (int rr = 0; rr < 4; rr++) {
                const float val = acc[sm][sn][rr] + bval;
                if constexpr (OUTF32)
                    ((float*)C)[(size_t)(row + rr) * D_MODEL + col] = val;
                else
                    ((ushortT*)C)[(size_t)(row + rr) * D_MODEL + col] = f2bf(val);
            }
        }
    }
}

// ---------------------------------------------------------------------------
// RoPE in-place on bf16 q and k (validated in R5).
// ---------------------------------------------------------------------------
__global__ __launch_bounds__(256) void rope_kernel(
    ushortT* __restrict__ qb, ushortT* __restrict__ kb,
    const float* __restrict__ theta)
{
    const int tok = blockIdx.x;
    ushortT* p = (blockIdx.y ? kb : qb) + (size_t)tok * D_MODEL;
    const int t = tok & (SEQ - 1);
    const int tid = threadIdx.x;
    const int d = tid & 63;
    const int hb = tid >> 6;

    const float fr = (float)t * theta[d];
    const float s = sinf(fr);
    const float c = cosf(fr);

    float ve[4], vo[4];
    #pragma unroll
    for (int i = 0; i < 4; i++) {
        ushortT* ph = p + (i * 4 + hb) * HEAD_DIM;
        ve[i] = bf2f(ph[2 * d]);
        vo[i] = bf2f(ph[2 * d + 1]);
    }
    __syncthreads();
    #pragma unroll
    for (int i = 0; i < 4; i++) {
        ushortT* ph = p + (i * 4 + hb) * HEAD_DIM;
        ph[d]      = f2bf(ve[i] * c - vo[i] * s);
        ph[d + 64] = f2bf(ve[i] * s + vo[i] * c);
    }
}

// ---------------------------------------------------------------------------
// K fragment pre-pack: kf[((bh*128 + kt16)*4 + ks)*512 + lane*8 + j]
//   = K[b, t = kt16*16 + lr, h, d = ks*32 + quad*8 + j]
// Flash then loads B-frags as one coalesced 1KB wave read.
// ---------------------------------------------------------------------------
__global__ __launch_bounds__(256) void kpack_kernel(
    const ushortT* __restrict__ k, ushortT* __restrict__ kf)
{
    const int kt16 = blockIdx.x;     // 0..127
    const int bh   = blockIdx.y;     // 0..31
    const int b = bh >> 4, h = bh & 15;
    const int tid = threadIdx.x;
    const int ks = tid >> 6, lane = tid & 63;
    const int lr = lane & 15, quad = lane >> 4;
    short8 v = *(const short8*)(
        k + (size_t)(b * SEQ + kt16 * 16 + lr) * D_MODEL + h * HEAD_DIM + ks * 32 + quad * 8);
    *(short8*)(kf + ((size_t)(bh * 128 + kt16) * 4 + ks) * 512 + lane * 8) = v;
}

// ---------------------------------------------------------------------------
// V fragment pre-pack (fused transpose):
// vf[((bh*8 + rt)*64 + ct)*512 + lane*8 + j] = V[b, t = ct*32+quad*8+j, h, d = rt*16+lr]
// ---------------------------------------------------------------------------
__global__ __launch_bounds__(256) void vpack_kernel(
    const ushortT* __restrict__ v, ushortT* __restrict__ vf)
{
    __shared__ ushortT tile[32][136];   // [t][d], padded
    const int ct = blockIdx.x;          // 0..63 (t / 32)
    const int bh = blockIdx.y;
    const int b = bh >> 4, h = bh & 15;
    const int tid = threadIdx.x;

    const int tt = tid >> 3;            // 0..31
    const int dc = (tid & 7) * 16;
    const ushortT* src = v + (size_t)(b * SEQ + ct * 32 + tt) * D_MODEL + h * HEAD_DIM + dc;
    *(short8*)&tile[tt][dc]     = *(const short8*)src;
    *(short8*)&tile[tt][dc + 8] = *(const short8*)(src + 8);
    __syncthreads();

    const int w = tid >> 6, lane = tid & 63;
    const int lr = lane & 15, quad = lane >> 4;
    #pragma unroll
    for (int p = 0; p < 2; p++) {
        const int rt = w + p * 4;       // 0..7
        short8 out;
        #pragma unroll
        for (int j = 0; j < 8; j++)
            out[j] = (short)tile[quad * 8 + j][rt * 16 + lr];
        *(short8*)(vf + ((size_t)(bh * 8 + rt) * 64 + ct) * 512 + lane * 8) = out;
    }
}

// ---------------------------------------------------------------------------
// Barrier-free MFMA flash attention with pre-packed K/V frags and paired
// q-tiles: block bx handles qt = bx and qt = 31-bx (uniform 33 K-tiles).
// ---------------------------------------------------------------------------
__global__ __launch_bounds__(256) void flash_attn2(
    const ushortT* __restrict__ q, const ushortT* __restrict__ kf,
    const ushortT* __restrict__ vf, ushortT* __restrict__ ctx)
{
    __shared__ short Pl[4][16][72];      // per-wave P transpose buffer

    const int bh = blockIdx.y;
    const int b = bh >> 4, h = bh & 15;
    const size_t base = (size_t)b * SEQ * D_MODEL + h * HEAD_DIM;
    const size_t kfb = (size_t)bh * 128 * 4 * 512;
    const size_t vfb = (size_t)bh * 8 * 64 * 512;
    const int tid = threadIdx.x;
    const int w = tid >> 6, lane = tid & 63;
    const int lr = lane & 15, quad = lane >> 4;
    short* myP = &Pl[w][0][0];

    for (int pass = 0; pass < 2; pass++) {
        const int qt = (pass == 0) ? blockIdx.x : (SEQ / 64 - 1 - blockIdx.x);
        const int q0 = qt * 64 + w * 16;

        // Q A-frags, 1/sqrt(HD) folded in
        short8 Qf[4];
        {
            const ushortT* qrow = q + base + (size_t)(q0 + lr) * D_MODEL + quad * 8;
            #pragma unroll
            for (int ks = 0; ks < 4; ks++) {
                short8 raw = *(const short8*)(qrow + ks * 32);
                #pragma unroll
                for (int j = 0; j < 8; j++)
                    Qf[ks][j] = (short)f2bf(bf2f((ushortT)raw[j]) * 0.08838834764831845f);
            }
        }

        floatx4 Of[8];
        #pragma unroll
        for (int i = 0; i < 8; i++) Of[i] = (floatx4){0.f, 0.f, 0.f, 0.f};
        float m_i[4] = {-INFINITY, -INFINITY, -INFINITY, -INFINITY};
        float l_i[4] = {0.f, 0.f, 0.f, 0.f};

        for (int kt0 = 0; kt0 <= qt * 64; kt0 += 64) {
            // --- S = Q K^T: coalesced frag loads from kf ---
            floatx4 Sf[4];
            #pragma unroll
            for (int sub = 0; sub < 4; sub++) {
                floatx4 acc = {0.f, 0.f, 0.f, 0.f};
                const ushortT* kp = kf + kfb + ((size_t)(kt0 / 16 + sub) * 4) * 512 + lane * 8;
                #pragma unroll
                for (int ks = 0; ks < 4; ks++) {
                    short8 Kf_ = *(const short8*)(kp + ks * 512);
                    acc = __builtin_amdgcn_mfma_f32_16x16x32_bf16(Qf[ks], Kf_, acc, 0, 0, 0);
                }
                Sf[sub] = acc;
            }

            // --- causal mask (diagonal tile only) ---
            if (kt0 == qt * 64) {
                #pragma unroll
                for (int sub = 0; sub < 4; sub++) {
                    const int ktg = kt0 + sub * 16 + lr;
                    #pragma unroll
                    for (int i = 0; i < 4; i++)
                        if (ktg > q0 + quad * 4 + i) Sf[sub][i] = -1e30f;
                }
            }

            // --- online softmax (row stats within one quad) ---
            float mn[4], alpha[4], rs[4];
            #pragma unroll
            for (int i = 0; i < 4; i++) {
                float t = fmaxf(fmaxf(Sf[0][i], Sf[1][i]), fmaxf(Sf[2][i], Sf[3][i]));
                t = fmaxf(t, __shfl_xor(t, 1));
                t = fmaxf(t, __shfl_xor(t, 2));
                t = fmaxf(t, __shfl_xor(t, 4));
                t = fmaxf(t, __shfl_xor(t, 8));
                mn[i] = fmaxf(m_i[i], t);
                alpha[i] = __expf(m_i[i] - mn[i]);
                m_i[i] = mn[i];
                rs[i] = 0.f;
            }
            #pragma unroll
            for (int sub = 0; sub < 4; sub++) {
                #pragma unroll
                for (int i = 0; i < 4; i++) {
                    const float p = __expf(Sf[sub][i] - mn[i]);
                    rs[i] += p;
                    myP[(quad * 4 + i) * 72 + sub * 16 + lr] = (short)f2bf(p);
                }
            }
            #pragma unroll
            for (int i = 0; i < 4; i++) {
                float t = rs[i];
                t += __shfl_xor(t, 1);
                t += __shfl_xor(t, 2);
                t += __shfl_xor(t, 4);
                t += __shfl_xor(t, 8);
                l_i[i] = l_i[i] * alpha[i] + t;
            }
            #pragma unroll
            for (int dsub = 0; dsub < 8; dsub++)
                #pragma unroll
                for (int i = 0; i < 4; i++) Of[dsub][i] *= alpha[i];

            // --- P: C-layout -> A-layout via wave-private LDS ---
            asm volatile("s_waitcnt lgkmcnt(0)" ::: "memory");
            short8 Pf0 = *(const short8*)(myP + lr * 72 + quad * 8);
            short8 Pf1 = *(const short8*)(myP + lr * 72 + 32 + quad * 8);

            // --- O += P V: coalesced frag loads from vf ---
            #pragma unroll
            for (int dsub = 0; dsub < 8; dsub++) {
                const ushortT* vp = vf + vfb + ((size_t)dsub * 64 + (kt0 >> 5)) * 512 + lane * 8;
                short8 V0 = *(const short8*)vp;
                short8 V1 = *(const short8*)(vp + 512);
                Of[dsub] = __builtin_amdgcn_mfma_f32_16x16x32_bf16(Pf0, V0, Of[dsub], 0, 0, 0);
                Of[dsub] = __builtin_amdgcn_mfma_f32_16x16x32_bf16(Pf1, V1, Of[dsub], 0, 0, 0);
            }
        }

        // --- epilogue ---
        float inv[4];
        #pragma unroll
        for (int i = 0; i < 4; i++) inv[i] = 1.f / l_i[i];
        #pragma unroll
        for (int dsub = 0; dsub < 8; dsub++)
            #pragma unroll
            for (int i = 0; i < 4; i++)
                ctx[base + (size_t)(q0 + quad * 4 + i) * D_MODEL + dsub * 16 + lr] =
                    f2bf(Of[dsub][i] * inv[i]);
    }
}

// ---------------------------------------------------------------------------
extern "C" void kernel_launch(void* const* d_in, const int* in_sizes, int n_in,
                              void* d_out, int out_size, void* d_ws, size_t ws_size,
                              hipStream_t stream) {
    const void*  x     = d_in[0];
    const void*  Wq    = d_in[1];
    const void*  Wk    = d_in[2];
    const void*  Wv    = d_in[3];
    const void*  Wo    = d_in[4];
    const float* bo    = (const float*)d_in[5];
    const float* theta = (const float*)d_in[6];

    ushortT* ws  = (ushortT*)d_ws;
    ushortT* qb  = ws;                     // Q (bf16)
    ushortT* kb  = ws + QKV_ELEMS;         // K; reused as vf after kpack
    ushortT* vb  = ws + 2 * QKV_ELEMS;     // V; reused as ctx after vpack
    ushortT* kfb = ws + 3 * QKV_ELEMS;     // K frags

    // 1. QKV projections (fp32 in, bf16 out)
    gemm128<false, false, false><<<dim3(D_MODEL / 128, M_TOK / 128, 3), 256, 0, stream>>>(
        x, Wq, Wk, Wv, qb, kb, vb, nullptr);

    // 2. RoPE on q and k
    rope_kernel<<<dim3(M_TOK, 2), 256, 0, stream>>>(qb, kb, theta);

    // 3. K fragment pack: kb -> kfb
    kpack_kernel<<<dim3(SEQ / 16, BATCH * NUM_HEADS), 256, 0, stream>>>(kb, kfb);

    // 4. V fragment pack (fused transpose): vb -> vf (overlays dead kb)
    vpack_kernel<<<dim3(SEQ / 32, BATCH * NUM_HEADS), 256, 0, stream>>>(vb, kb);

    // 5. Flash attention -> ctx (overlays dead vb)
    flash_attn2<<<dim3(SEQ / 128, BATCH * NUM_HEADS), 256, 0, stream>>>(
        qb, kfb, kb, vb);

    // 6. Output projection + bias (bf16 A, fp32 W, fp32 out)
    gemm128<true, false, true><<<dim3(D_MODEL / 128, M_TOK / 128, 1), 256, 0, stream>>>(
        vb, Wo, Wo, Wo, d_out, d_out, d_out, bo);
}